// Round 1
// baseline (521.967 us; speedup 1.0000x reference)
//
#include <hip/hip_runtime.h>
#include <hip/hip_bf16.h>
#include <math.h>

// Problem constants (match reference)
#define BB 32
#define HQ 32
#define HKV 8
#define DD 128
#define PAGE_SZ 16
#define PAGES_PER_SEQ 128
#define MAX_LEN 2048
#define GG 4            // HQ / HKV
#define NCHUNK 8        // MAX_LEN / CHUNK
#define CHUNK 256       // tokens per split-K chunk
#define SCALING 0.08838834764831845f
#define CAP 50.0f
#define WS_STRIDE 520   // 4 m + 4 l + 512 o floats per partial

// One block per (b, kv_head, chunk). 256 threads = 4 waves = 8 half-waves.
// Each half-wave (32 lanes x float4) loads one 512B K/V row per iteration.
__global__ __launch_bounds__(256, 4) void attn_partial(
    const float* __restrict__ q,        // [B, HQ*D]
    const float* __restrict__ knew,     // [B, HKV*D]
    const float* __restrict__ vnew,     // [B, HKV*D]
    const float* __restrict__ k_cache,  // [NUM_PAGES, PAGE_SZ, HKV, D]
    const float* __restrict__ v_cache,
    const int* __restrict__ page_table, // [B, PAGES_PER_SEQ]
    const int* __restrict__ seq_lens,   // [B]
    float* __restrict__ ws)
{
    const int idx = blockIdx.x;
    const int c  = idx % NCHUNK;
    const int bh = idx / NCHUNK;
    const int h  = bh % HKV;
    const int b  = bh / HKV;

    const int L  = seq_lens[b];
    const int t0 = c * CHUNK;
    const int t1 = min(t0 + CHUNK, L);
    float* wsb = ws + (size_t)idx * WS_STRIDE;

    if (t0 >= t1) {
        // empty chunk: mark l=0 so combine skips it (block-uniform early exit)
        if (threadIdx.x < GG) { wsb[threadIdx.x] = -INFINITY; wsb[GG + threadIdx.x] = 0.0f; }
        return;
    }
    const int NT = t1 - t0;

    __shared__ float s_q[GG][DD];            // 2 KB
    __shared__ float s_sc[GG][CHUNK];        // 4 KB (scores, then p=exp(s-m))
    __shared__ float s_red[8][GG * DD];      // 16 KB (cross-halfwave O reduce)
    __shared__ int   s_pages[CHUNK / PAGE_SZ];
    __shared__ float s_m[GG], s_l[GG];

    const int tid = threadIdx.x;

    // stage q (4 heads x 128) and the chunk's page-table slice into LDS
    for (int i = tid; i < GG * DD; i += 256) {
        int g = i / DD, d = i % DD;
        s_q[g][d] = q[(size_t)b * (HQ * DD) + (h * GG + g) * DD + d];
    }
    if (tid < CHUNK / PAGE_SZ)
        s_pages[tid] = page_table[b * PAGES_PER_SEQ + t0 / PAGE_SZ + tid];
    __syncthreads();

    const int hw = tid >> 5;   // half-wave 0..7
    const int ln = tid & 31;   // lane within half-wave

    float4 qf[GG];
    #pragma unroll
    for (int g = 0; g < GG; g++) qf[g] = *(const float4*)&s_q[g][4 * ln];

    // ---- phase 1: capped scores into LDS (reads K once) ----
    for (int t = t0 + hw; t < t1; t += 8) {
        const float4* krow;
        if (t == L - 1) {
            krow = (const float4*)&knew[(size_t)b * (HKV * DD) + h * DD];
        } else {
            int page = s_pages[(t - t0) >> 4];
            int slot = t & (PAGE_SZ - 1);
            krow = (const float4*)&k_cache[((size_t)page * PAGE_SZ + slot) * (HKV * DD) + h * DD];
        }
        float4 kv = krow[ln];
        float dots[GG];
        #pragma unroll
        for (int g = 0; g < GG; g++)
            dots[g] = kv.x * qf[g].x + kv.y * qf[g].y + kv.z * qf[g].z + kv.w * qf[g].w;
        #pragma unroll
        for (int m = 1; m < 32; m <<= 1) {
            #pragma unroll
            for (int g = 0; g < GG; g++) dots[g] += __shfl_xor(dots[g], m);
        }
        if (ln == 0) {
            #pragma unroll
            for (int g = 0; g < GG; g++) {
                float s = dots[g] * SCALING;
                s_sc[g][t - t0] = CAP * tanhf(s * (1.0f / CAP));
            }
        }
    }
    __syncthreads();

    // ---- phase 1.5: per-g max + exp + sum (one wave per g) ----
    {
        int g  = tid >> 6;     // 0..3
        int wl = tid & 63;
        float mx = -INFINITY;
        for (int t = wl; t < NT; t += 64) mx = fmaxf(mx, s_sc[g][t]);
        #pragma unroll
        for (int m = 1; m < 64; m <<= 1) mx = fmaxf(mx, __shfl_xor(mx, m));
        float sum = 0.0f;
        for (int t = wl; t < NT; t += 64) {
            float e = __expf(s_sc[g][t] - mx);
            s_sc[g][t] = e;
            sum += e;
        }
        #pragma unroll
        for (int m = 1; m < 64; m <<= 1) sum += __shfl_xor(sum, m);
        if (wl == 0) { s_m[g] = mx; s_l[g] = sum; }
    }
    __syncthreads();

    // ---- phase 2: O += p * V (reads V once) ----
    float4 acc[GG];
    #pragma unroll
    for (int g = 0; g < GG; g++) acc[g] = make_float4(0.f, 0.f, 0.f, 0.f);
    for (int t = t0 + hw; t < t1; t += 8) {
        const float4* vrow;
        if (t == L - 1) {
            vrow = (const float4*)&vnew[(size_t)b * (HKV * DD) + h * DD];
        } else {
            int page = s_pages[(t - t0) >> 4];
            int slot = t & (PAGE_SZ - 1);
            vrow = (const float4*)&v_cache[((size_t)page * PAGE_SZ + slot) * (HKV * DD) + h * DD];
        }
        float4 vv = vrow[ln];
        #pragma unroll
        for (int g = 0; g < GG; g++) {
            float p = s_sc[g][t - t0];
            acc[g].x += p * vv.x; acc[g].y += p * vv.y;
            acc[g].z += p * vv.z; acc[g].w += p * vv.w;
        }
    }
    #pragma unroll
    for (int g = 0; g < GG; g++)
        *(float4*)&s_red[hw][g * DD + 4 * ln] = acc[g];
    __syncthreads();

    // reduce 8 half-waves -> partial O, write workspace
    for (int i = tid; i < GG * DD; i += 256) {
        float s = 0.f;
        #pragma unroll
        for (int w = 0; w < 8; w++) s += s_red[w][i];
        wsb[8 + i] = s;
    }
    if (tid < GG) { wsb[tid] = s_m[tid]; wsb[GG + tid] = s_l[tid]; }
}

// One block per (b, kv_head); 512 threads = one (g, d) element each.
__global__ __launch_bounds__(512) void attn_combine(
    const float* __restrict__ ws, float* __restrict__ out)
{
    const int bh = blockIdx.x;
    const int h  = bh % HKV;
    const int b  = bh / HKV;
    const int tid = threadIdx.x;   // 0..511
    const int g = tid / DD;
    const int d = tid % DD;

    float mv[NCHUNK], lv[NCHUNK];
    float M = -INFINITY;
    #pragma unroll
    for (int c = 0; c < NCHUNK; c++) {
        const float* wsb = ws + (size_t)(bh * NCHUNK + c) * WS_STRIDE;
        mv[c] = wsb[g];
        lv[c] = wsb[GG + g];
        if (lv[c] > 0.0f) M = fmaxf(M, mv[c]);
    }
    float lsum = 0.0f, osum = 0.0f;
    #pragma unroll
    for (int c = 0; c < NCHUNK; c++) {
        if (lv[c] > 0.0f) {
            const float* wsb = ws + (size_t)(bh * NCHUNK + c) * WS_STRIDE;
            float a = __expf(mv[c] - M);
            lsum += lv[c] * a;
            osum += wsb[8 + g * DD + d] * a;
        }
    }
    out[(size_t)b * (HQ * DD) + (h * GG + g) * DD + d] = osum / lsum;
}

extern "C" void kernel_launch(void* const* d_in, const int* in_sizes, int n_in,
                              void* d_out, int out_size, void* d_ws, size_t ws_size,
                              hipStream_t stream) {
    const float* q       = (const float*)d_in[0];
    const float* k       = (const float*)d_in[1];
    const float* v       = (const float*)d_in[2];
    const float* k_cache = (const float*)d_in[3];
    const float* v_cache = (const float*)d_in[4];
    const int* page_table = (const int*)d_in[5];
    const int* seq_lens   = (const int*)d_in[6];
    float* out = (float*)d_out;
    float* ws  = (float*)d_ws;   // needs B*HKV*NCHUNK*520*4 = 4.26 MB

    attn_partial<<<BB * HKV * NCHUNK, 256, 0, stream>>>(
        q, k, v, k_cache, v_cache, page_table, seq_lens, ws);
    attn_combine<<<BB * HKV, 512, 0, stream>>>(ws, out);
}

// Round 2
// 482.289 us; speedup vs baseline: 1.0823x; 1.0823x over previous
//
#include <hip/hip_runtime.h>
#include <hip/hip_bf16.h>
#include <math.h>

// Problem constants (match reference)
#define BB 32
#define HQ 32
#define HKV 8
#define DD 128
#define PAGE_SZ 16
#define PAGES_PER_SEQ 128
#define MAX_LEN 2048
#define GG 4            // HQ / HKV
#define NCHUNK 8        // MAX_LEN / CHUNK
#define CHUNK 256       // tokens per split-K chunk
#define SCALING 0.08838834764831845f
#define CAP 50.0f
#define WS_STRIDE 520   // 4 m + 4 l + 512 o floats per partial

// One block per (b, kv_head, chunk). 256 threads = 4 waves = 8 half-waves.
// Batching: each half-wave handles 4 tokens per iteration (t, t+8, t+16, t+24)
// so 4 loads + 16 independent shuffle-reduce chains are in flight at once.
__global__ __launch_bounds__(256, 4) void attn_partial(
    const float* __restrict__ q,        // [B, HQ*D]
    const float* __restrict__ knew,     // [B, HKV*D]
    const float* __restrict__ vnew,     // [B, HKV*D]
    const float* __restrict__ k_cache,  // [NUM_PAGES, PAGE_SZ, HKV, D]
    const float* __restrict__ v_cache,
    const int* __restrict__ page_table, // [B, PAGES_PER_SEQ]
    const int* __restrict__ seq_lens,   // [B]
    float* __restrict__ ws)
{
    const int idx = blockIdx.x;
    const int c  = idx % NCHUNK;
    const int bh = idx / NCHUNK;
    const int h  = bh % HKV;
    const int b  = bh / HKV;

    const int L  = seq_lens[b];
    const int t0 = c * CHUNK;
    const int t1 = min(t0 + CHUNK, L);
    float* wsb = ws + (size_t)idx * WS_STRIDE;

    if (t0 >= t1) {
        if (threadIdx.x < GG) { wsb[threadIdx.x] = -INFINITY; wsb[GG + threadIdx.x] = 0.0f; }
        return;
    }
    const int NT = t1 - t0;

    __shared__ float s_q[GG][DD];            // 2 KB
    __shared__ float s_sc[GG][CHUNK];        // 4 KB (raw dots -> capped -> p)
    __shared__ float s_red[8][GG * DD];      // 16 KB (cross-halfwave O reduce)
    __shared__ int   s_pages[CHUNK / PAGE_SZ];
    __shared__ float s_m[GG], s_l[GG];

    const int tid = threadIdx.x;

    for (int i = tid; i < GG * DD; i += 256) {
        int g = i / DD, d = i % DD;
        s_q[g][d] = q[(size_t)b * (HQ * DD) + (h * GG + g) * DD + d];
    }
    if (tid < CHUNK / PAGE_SZ)
        s_pages[tid] = page_table[b * PAGES_PER_SEQ + t0 / PAGE_SZ + tid];
    __syncthreads();

    const int hw = tid >> 5;   // half-wave 0..7
    const int ln = tid & 31;   // lane within half-wave

    float4 qf[GG];
    #pragma unroll
    for (int g = 0; g < GG; g++) qf[g] = *(const float4*)&s_q[g][4 * ln];

    const float4* knew_row = (const float4*)&knew[(size_t)b * (HKV * DD) + h * DD];
    const float4* vnew_row = (const float4*)&vnew[(size_t)b * (HKV * DD) + h * DD];

    // ---- phase 1: raw dots into LDS, 4 tokens in flight per half-wave ----
    for (int i = 0; i < CHUNK / 32; i++) {
        const int tbase = t0 + i * 32 + hw;
        if (tbase >= t1) break;

        float4 kv[4];
        int   trel[4];
        bool  vld[4];
        #pragma unroll
        for (int j = 0; j < 4; j++) {
            int t = tbase + j * 8;
            vld[j] = (t < t1);
            int tc = vld[j] ? t : tbase;           // clamp to a valid token
            trel[j] = tc - t0;
            const float4* krow;
            if (tc == L - 1) {
                krow = knew_row;
            } else {
                int page = s_pages[trel[j] >> 4];
                int slot = tc & (PAGE_SZ - 1);
                krow = (const float4*)&k_cache[((size_t)page * PAGE_SZ + slot) * (HKV * DD) + h * DD];
            }
            kv[j] = krow[ln];
        }

        float dots[4][GG];
        #pragma unroll
        for (int j = 0; j < 4; j++) {
            #pragma unroll
            for (int g = 0; g < GG; g++)
                dots[j][g] = kv[j].x * qf[g].x + kv[j].y * qf[g].y
                           + kv[j].z * qf[g].z + kv[j].w * qf[g].w;
        }
        #pragma unroll
        for (int m = 1; m < 32; m <<= 1) {
            #pragma unroll
            for (int j = 0; j < 4; j++)
                #pragma unroll
                for (int g = 0; g < GG; g++)
                    dots[j][g] += __shfl_xor(dots[j][g], m);
        }
        if (ln == 0) {
            #pragma unroll
            for (int j = 0; j < 4; j++)
                if (vld[j])
                    #pragma unroll
                    for (int g = 0; g < GG; g++)
                        s_sc[g][trel[j]] = dots[j][g];
        }
    }
    __syncthreads();

    // ---- phase 1.5: scale + cap + max + exp + sum (one wave per g) ----
    {
        int g  = tid >> 6;     // 0..3
        int wl = tid & 63;
        float mx = -INFINITY;
        for (int t = wl; t < NT; t += 64) {
            float s = s_sc[g][t];
            s = CAP * tanhf(s * (SCALING * (1.0f / CAP)));
            s_sc[g][t] = s;
            mx = fmaxf(mx, s);
        }
        #pragma unroll
        for (int m = 1; m < 64; m <<= 1) mx = fmaxf(mx, __shfl_xor(mx, m));
        float sum = 0.0f;
        for (int t = wl; t < NT; t += 64) {
            float e = __expf(s_sc[g][t] - mx);
            s_sc[g][t] = e;
            sum += e;
        }
        #pragma unroll
        for (int m = 1; m < 64; m <<= 1) sum += __shfl_xor(sum, m);
        if (wl == 0) { s_m[g] = mx; s_l[g] = sum; }
    }
    __syncthreads();

    // ---- phase 2: O += p * V, 4 tokens in flight per half-wave ----
    float4 acc[GG];
    #pragma unroll
    for (int g = 0; g < GG; g++) acc[g] = make_float4(0.f, 0.f, 0.f, 0.f);

    for (int i = 0; i < CHUNK / 32; i++) {
        const int tbase = t0 + i * 32 + hw;
        if (tbase >= t1) break;

        float4 vv[4];
        int   trel[4];
        bool  vld[4];
        #pragma unroll
        for (int j = 0; j < 4; j++) {
            int t = tbase + j * 8;
            vld[j] = (t < t1);
            int tc = vld[j] ? t : tbase;
            trel[j] = tc - t0;
            const float4* vrow;
            if (tc == L - 1) {
                vrow = vnew_row;
            } else {
                int page = s_pages[trel[j] >> 4];
                int slot = tc & (PAGE_SZ - 1);
                vrow = (const float4*)&v_cache[((size_t)page * PAGE_SZ + slot) * (HKV * DD) + h * DD];
            }
            vv[j] = vrow[ln];
        }
        float p[4][GG];
        #pragma unroll
        for (int j = 0; j < 4; j++)
            #pragma unroll
            for (int g = 0; g < GG; g++)
                p[j][g] = vld[j] ? s_sc[g][trel[j]] : 0.0f;

        #pragma unroll
        for (int j = 0; j < 4; j++) {
            #pragma unroll
            for (int g = 0; g < GG; g++) {
                acc[g].x += p[j][g] * vv[j].x; acc[g].y += p[j][g] * vv[j].y;
                acc[g].z += p[j][g] * vv[j].z; acc[g].w += p[j][g] * vv[j].w;
            }
        }
    }
    #pragma unroll
    for (int g = 0; g < GG; g++)
        *(float4*)&s_red[hw][g * DD + 4 * ln] = acc[g];
    __syncthreads();

    for (int i = tid; i < GG * DD; i += 256) {
        float s = 0.f;
        #pragma unroll
        for (int w = 0; w < 8; w++) s += s_red[w][i];
        wsb[8 + i] = s;
    }
    if (tid < GG) { wsb[tid] = s_m[tid]; wsb[GG + tid] = s_l[tid]; }
}

// One block per (b, kv_head); 512 threads = one (g, d) element each.
__global__ __launch_bounds__(512) void attn_combine(
    const float* __restrict__ ws, float* __restrict__ out)
{
    const int bh = blockIdx.x;
    const int h  = bh % HKV;
    const int b  = bh / HKV;
    const int tid = threadIdx.x;   // 0..511
    const int g = tid / DD;
    const int d = tid % DD;

    float mv[NCHUNK], lv[NCHUNK];
    float M = -INFINITY;
    #pragma unroll
    for (int c = 0; c < NCHUNK; c++) {
        const float* wsb = ws + (size_t)(bh * NCHUNK + c) * WS_STRIDE;
        mv[c] = wsb[g];
        lv[c] = wsb[GG + g];
        if (lv[c] > 0.0f) M = fmaxf(M, mv[c]);
    }
    float lsum = 0.0f, osum = 0.0f;
    #pragma unroll
    for (int c = 0; c < NCHUNK; c++) {
        if (lv[c] > 0.0f) {
            const float* wsb = ws + (size_t)(bh * NCHUNK + c) * WS_STRIDE;
            float a = __expf(mv[c] - M);
            lsum += lv[c] * a;
            osum += wsb[8 + g * DD + d] * a;
        }
    }
    out[(size_t)b * (HQ * DD) + (h * GG + g) * DD + d] = osum / lsum;
}

extern "C" void kernel_launch(void* const* d_in, const int* in_sizes, int n_in,
                              void* d_out, int out_size, void* d_ws, size_t ws_size,
                              hipStream_t stream) {
    const float* q       = (const float*)d_in[0];
    const float* k       = (const float*)d_in[1];
    const float* v       = (const float*)d_in[2];
    const float* k_cache = (const float*)d_in[3];
    const float* v_cache = (const float*)d_in[4];
    const int* page_table = (const int*)d_in[5];
    const int* seq_lens   = (const int*)d_in[6];
    float* out = (float*)d_out;
    float* ws  = (float*)d_ws;   // needs B*HKV*NCHUNK*520*4 = 4.26 MB

    attn_partial<<<BB * HKV * NCHUNK, 256, 0, stream>>>(
        q, k, v, k_cache, v_cache, page_table, seq_lens, ws);
    attn_combine<<<BB * HKV, 512, 0, stream>>>(ws, out);
}

// Round 3
// 475.909 us; speedup vs baseline: 1.0968x; 1.0134x over previous
//
#include <hip/hip_runtime.h>
#include <hip/hip_bf16.h>
#include <math.h>

// Problem constants (match reference)
#define BB 32
#define HQ 32
#define HKV 8
#define DD 128
#define PAGE_SZ 16
#define PAGES_PER_SEQ 128
#define MAX_LEN 2048
#define GG 4            // HQ / HKV
#define NCHUNK 8        // MAX_LEN / CHUNK
#define CHUNK 256       // tokens per split-K chunk
#define SCALING 0.08838834764831845f
#define CAP 50.0f
#define WS_STRIDE 520   // 4 m + 4 l + 512 o floats per partial

// Sum over each 8-lane group via DPP row_shr (VALU pipe, no LDS traffic).
// After shr1+shr2+shr4, lanes 7 and 15 (mod 16) hold their group's sum.
__device__ __forceinline__ float dpp8_sum(float x) {
    int t;
    t = __builtin_amdgcn_update_dpp(0, __float_as_int(x), 0x111, 0xF, 0xF, true);
    x += __int_as_float(t);
    t = __builtin_amdgcn_update_dpp(0, __float_as_int(x), 0x112, 0xF, 0xF, true);
    x += __int_as_float(t);
    t = __builtin_amdgcn_update_dpp(0, __float_as_int(x), 0x114, 0xF, 0xF, true);
    x += __int_as_float(t);
    return x;
}

// One block per (b, kv_head, chunk). 256 threads = 4 waves.
// Phase 1: 8 lanes per token (8 tokens per wave per iter), in-lane partial
//          dots + 3-step DPP reduce. K loads software-pipelined 2-deep.
// Phase 2: half-wave per token, d-per-lane (shuffle-free), 4 tokens batched.
__global__ __launch_bounds__(256, 4) void attn_partial(
    const float* __restrict__ q,        // [B, HQ*D]
    const float* __restrict__ knew,     // [B, HKV*D]
    const float* __restrict__ vnew,     // [B, HKV*D]
    const float* __restrict__ k_cache,  // [NUM_PAGES, PAGE_SZ, HKV, D]
    const float* __restrict__ v_cache,
    const int* __restrict__ page_table, // [B, PAGES_PER_SEQ]
    const int* __restrict__ seq_lens,   // [B]
    float* __restrict__ ws)
{
    const int idx = blockIdx.x;
    const int c  = idx % NCHUNK;
    const int bh = idx / NCHUNK;
    const int h  = bh % HKV;
    const int b  = bh / HKV;

    const int L  = seq_lens[b];
    const int t0 = c * CHUNK;
    const int t1 = min(t0 + CHUNK, L);
    float* wsb = ws + (size_t)idx * WS_STRIDE;

    if (t0 >= t1) {
        if (threadIdx.x < GG) { wsb[threadIdx.x] = -INFINITY; wsb[GG + threadIdx.x] = 0.0f; }
        return;
    }
    const int NT = t1 - t0;

    __shared__ float s_q[GG][DD];            // 2 KB
    __shared__ float s_sc[GG][CHUNK];        // 4 KB (raw dots -> capped -> p)
    __shared__ float s_red[8][GG * DD];      // 16 KB (cross-halfwave O reduce)
    __shared__ int   s_pages[CHUNK / PAGE_SZ];
    __shared__ float s_m[GG], s_l[GG];

    const int tid = threadIdx.x;

    for (int i = tid; i < GG * DD; i += 256) {
        int g = i / DD, d = i % DD;
        s_q[g][d] = q[(size_t)b * (HQ * DD) + (h * GG + g) * DD + d];
    }
    if (tid < CHUNK / PAGE_SZ)
        s_pages[tid] = page_table[b * PAGES_PER_SEQ + t0 / PAGE_SZ + tid];
    __syncthreads();

    const float* knew_row = &knew[(size_t)b * (HKV * DD) + h * DD];
    const float* vnew_row = &vnew[(size_t)b * (HKV * DD) + h * DD];

    // ---- phase 1: 8 lanes per token, DPP reduce ----
    {
        const int wv = tid >> 6;   // wave 0..3
        const int ln = tid & 63;
        const int tg = ln >> 3;    // token group 0..7 within wave
        const int lg = ln & 7;     // lane in group: owns d in [lg*4 + 32p, ...)

        float4 qf[GG][4];
        #pragma unroll
        for (int g = 0; g < GG; g++)
            #pragma unroll
            for (int p = 0; p < 4; p++)
                qf[g][p] = *(const float4*)&s_q[g][p * 32 + lg * 4];

        const int niter = (NT + 31) >> 5;  // 1..8; each iter covers 32 tokens

#define LOAD_K(I, KV, WT) do {                                                \
        int t_ = t0 + (I) * 32 + wv * 8 + tg;                                 \
        bool vld_ = t_ < t1;                                                  \
        int tc_ = vld_ ? t_ : (t1 - 1);                                       \
        const float* row_;                                                    \
        if (tc_ == L - 1) row_ = knew_row;                                    \
        else {                                                                \
            int page_ = s_pages[(tc_ - t0) >> 4];                             \
            int slot_ = tc_ & (PAGE_SZ - 1);                                  \
            row_ = &k_cache[((size_t)page_ * PAGE_SZ + slot_) * (HKV * DD) + h * DD]; \
        }                                                                     \
        const float4* r4_ = (const float4*)row_;                              \
        KV[0] = r4_[lg]; KV[1] = r4_[8 + lg];                                 \
        KV[2] = r4_[16 + lg]; KV[3] = r4_[24 + lg];                           \
        WT = vld_ ? (t_ - t0) : -1;                                           \
    } while (0)

        float4 kva[4];
        int wta;
        LOAD_K(0, kva, wta);

        for (int i = 0; i < niter; i++) {
            float4 kvb[4];
            int wtb = -1;
            if (i + 1 < niter) LOAD_K(i + 1, kvb, wtb);

            float dots[GG];
            #pragma unroll
            for (int g = 0; g < GG; g++) {
                float s = 0.0f;
                #pragma unroll
                for (int p = 0; p < 4; p++)
                    s += kva[p].x * qf[g][p].x + kva[p].y * qf[g][p].y
                       + kva[p].z * qf[g][p].z + kva[p].w * qf[g][p].w;
                dots[g] = dpp8_sum(s);
            }
            if (lg == 7 && wta >= 0) {
                #pragma unroll
                for (int g = 0; g < GG; g++) s_sc[g][wta] = dots[g];
            }
            #pragma unroll
            for (int p = 0; p < 4; p++) kva[p] = kvb[p];
            wta = wtb;
        }
#undef LOAD_K
    }
    __syncthreads();

    // ---- phase 1.5: scale + cap + max + exp + sum (one wave per g) ----
    {
        int g  = tid >> 6;     // 0..3
        int wl = tid & 63;
        float mx = -INFINITY;
        for (int t = wl; t < NT; t += 64) {
            float s = s_sc[g][t];
            s = CAP * tanhf(s * (SCALING * (1.0f / CAP)));
            s_sc[g][t] = s;
            mx = fmaxf(mx, s);
        }
        #pragma unroll
        for (int m = 1; m < 64; m <<= 1) mx = fmaxf(mx, __shfl_xor(mx, m));
        float sum = 0.0f;
        for (int t = wl; t < NT; t += 64) {
            float e = __expf(s_sc[g][t] - mx);
            s_sc[g][t] = e;
            sum += e;
        }
        #pragma unroll
        for (int m = 1; m < 64; m <<= 1) sum += __shfl_xor(sum, m);
        if (wl == 0) { s_m[g] = mx; s_l[g] = sum; }
    }
    __syncthreads();

    // ---- phase 2: O += p * V, half-wave per token, 4 tokens in flight ----
    const int hw = tid >> 5;   // half-wave 0..7
    const int ln = tid & 31;

    float4 acc[GG];
    #pragma unroll
    for (int g = 0; g < GG; g++) acc[g] = make_float4(0.f, 0.f, 0.f, 0.f);

    for (int i = 0; i < CHUNK / 32; i++) {
        const int tbase = t0 + i * 32 + hw;
        if (t0 + i * 32 >= t1) break;

        float4 vv[4];
        int   trel[4];
        bool  vld[4];
        #pragma unroll
        for (int j = 0; j < 4; j++) {
            int t = tbase + j * 8;
            vld[j] = (t < t1);
            int tc = vld[j] ? t : tbase;
            trel[j] = tc - t0;
            const float4* vrow;
            if (tc == L - 1) {
                vrow = (const float4*)vnew_row;
            } else {
                int page = s_pages[trel[j] >> 4];
                int slot = tc & (PAGE_SZ - 1);
                vrow = (const float4*)&v_cache[((size_t)page * PAGE_SZ + slot) * (HKV * DD) + h * DD];
            }
            vv[j] = vrow[ln];
        }
        float p[4][GG];
        #pragma unroll
        for (int j = 0; j < 4; j++)
            #pragma unroll
            for (int g = 0; g < GG; g++)
                p[j][g] = vld[j] ? s_sc[g][trel[j]] : 0.0f;

        #pragma unroll
        for (int j = 0; j < 4; j++) {
            #pragma unroll
            for (int g = 0; g < GG; g++) {
                acc[g].x += p[j][g] * vv[j].x; acc[g].y += p[j][g] * vv[j].y;
                acc[g].z += p[j][g] * vv[j].z; acc[g].w += p[j][g] * vv[j].w;
            }
        }
    }
    #pragma unroll
    for (int g = 0; g < GG; g++)
        *(float4*)&s_red[hw][g * DD + 4 * ln] = acc[g];
    __syncthreads();

    for (int i = tid; i < GG * DD; i += 256) {
        float s = 0.f;
        #pragma unroll
        for (int w = 0; w < 8; w++) s += s_red[w][i];
        wsb[8 + i] = s;
    }
    if (tid < GG) { wsb[tid] = s_m[tid]; wsb[GG + tid] = s_l[tid]; }
}

// One block per (b, kv_head); 512 threads = one (g, d) element each.
__global__ __launch_bounds__(512) void attn_combine(
    const float* __restrict__ ws, float* __restrict__ out)
{
    const int bh = blockIdx.x;
    const int h  = bh % HKV;
    const int b  = bh / HKV;
    const int tid = threadIdx.x;   // 0..511
    const int g = tid / DD;
    const int d = tid % DD;

    float mv[NCHUNK], lv[NCHUNK];
    float M = -INFINITY;
    #pragma unroll
    for (int c = 0; c < NCHUNK; c++) {
        const float* wsb = ws + (size_t)(bh * NCHUNK + c) * WS_STRIDE;
        mv[c] = wsb[g];
        lv[c] = wsb[GG + g];
        if (lv[c] > 0.0f) M = fmaxf(M, mv[c]);
    }
    float lsum = 0.0f, osum = 0.0f;
    #pragma unroll
    for (int c = 0; c < NCHUNK; c++) {
        if (lv[c] > 0.0f) {
            const float* wsb = ws + (size_t)(bh * NCHUNK + c) * WS_STRIDE;
            float a = __expf(mv[c] - M);
            lsum += lv[c] * a;
            osum += wsb[8 + g * DD + d] * a;
        }
    }
    out[(size_t)b * (HQ * DD) + (h * GG + g) * DD + d] = osum / lsum;
}

extern "C" void kernel_launch(void* const* d_in, const int* in_sizes, int n_in,
                              void* d_out, int out_size, void* d_ws, size_t ws_size,
                              hipStream_t stream) {
    const float* q       = (const float*)d_in[0];
    const float* k       = (const float*)d_in[1];
    const float* v       = (const float*)d_in[2];
    const float* k_cache = (const float*)d_in[3];
    const float* v_cache = (const float*)d_in[4];
    const int* page_table = (const int*)d_in[5];
    const int* seq_lens   = (const int*)d_in[6];
    float* out = (float*)d_out;
    float* ws  = (float*)d_ws;   // needs B*HKV*NCHUNK*520*4 = 4.26 MB

    attn_partial<<<BB * HKV * NCHUNK, 256, 0, stream>>>(
        q, k, v, k_cache, v_cache, page_table, seq_lens, ws);
    attn_combine<<<BB * HKV, 512, 0, stream>>>(ws, out);
}